// Round 17
// baseline (1325.543 us; speedup 1.0000x reference)
//
#include <hip/hip_runtime.h>

typedef float  f32x4  __attribute__((ext_vector_type(4)));
typedef short  short8 __attribute__((ext_vector_type(8)));
typedef unsigned int uint;
typedef unsigned short ushort;

#define NT    512
#define SEQN  12
#define ROWS  64

// ws offsets (in 4-byte units)
#define OFF_PART   0          // [512][2][96] BN partials
#define OFF_SCALE  98304      // [96]
#define OFF_SHIFT  98400      // [96]
#define OFF_WG     98496      // 409600 u32: [q200][nq4][half2][lane64][4u32]; q=kt*20+c
#define OFF_WA     508096     // 66560 u32:  [s13][kt10][lane64][8u32]

#define WG_U32     409600
#define WA_U32     66560

// LDS layout (bytes)
#define L_HHI   0          // [64][320] ushort, swizzled (40960)
#define L_HLO   40960      // [64][320] ushort (40960)
#define L_B     81920      // 8 waves x ring4 x 2KB private staged B (65536)
#define L_Q     147456     // [64][12] f32 (3072)
#define L_TA    150528     // [64][12] f32 (3072)
#define L_SCS   153600     // [96] f32
#define L_SHS   153984     // [96] f32
#define L_WSA   154368     // [8][8] f32
#define L_BSA   154624     // [8] f32
#define SMEM_BYTES 154656
// phase-1 overlays: Win [96][97] f32 (37248) at byte 0 (inside h region);
// xn [64][96] f32 (24576) at L_B; y [64][96] f32 at L_B+24576

__device__ __forceinline__ float sigm_(float v) { return 1.f / (1.f + __expf(-v)); }
__device__ __forceinline__ float tanh_(float v) { float e = __expf(2.f * v); return 1.f - 2.f / (e + 1.f); }

__device__ __forceinline__ uint f2b(float v) {
    uint u = __float_as_uint(v);
    return (u + 0x7FFFu + ((u >> 16) & 1u)) >> 16;
}
__device__ __forceinline__ float b2f(uint b) { return __uint_as_float(b << 16); }
// swizzled byte offset into h arrays ([64][320] ushort)
__device__ __forceinline__ int haddr(int row, int u) {
    return ((row * 640 + u * 2) ^ ((row & 7) << 4));
}

__device__ __forceinline__ void gload_lds16(const void* src, void* dst) {
    __builtin_amdgcn_global_load_lds((const __attribute__((address_space(1))) void*)src,
                                     (__attribute__((address_space(3))) void*)dst, 16, 0, 0);
}

// ---------------- Kernel 1: BN partial sums ----------------
__global__ __launch_bounds__(192) void bn_partial_k(const float* __restrict__ x,
                                                    float* __restrict__ ws) {
    __shared__ float sm[2][2][96];
    int t = threadIdx.x;
    int half = t / 96, f = t - half * 96;
    int r0 = blockIdx.x * 64 + half * 32;
    float s1 = 0.f, s2 = 0.f;
    for (int r = 0; r < 32; ++r) {
        float v = x[(size_t)(r0 + r) * 96 + f];
        s1 += v; s2 += v * v;
    }
    sm[half][0][f] = s1; sm[half][1][f] = s2;
    __syncthreads();
    if (t < 96) {
        ws[OFF_PART + blockIdx.x * 192 + t]      = sm[0][0][t] + sm[1][0][t];
        ws[OFF_PART + blockIdx.x * 192 + 96 + t] = sm[0][1][t] + sm[1][1][t];
    }
}

// ---------------- Kernel 2: build bf16-split fragment tables ----------------
// tile (0..79): nq = tile/20, rem = tile%20, us = rem/4, g = rem%4
__device__ __forceinline__ float wg_val(int kt, int tile, int lane, int e,
                                        const float* W_hh, const float* W_ih,
                                        const float* b_ih, const float* b_hh) {
    int nq = tile / 20, rem = tile % 20;
    int us = rem / 4, g = rem & 3;
    int u = nq * 80 + us * 16 + (lane & 15);
    int k = kt * 32 + ((lane >> 4) << 3) + e;
    if (u >= 300) return 0.f;
    int gu = g * 300 + u;
    if (k < 300)  return W_hh[(size_t)gu * 300 + k];
    if (k == 300) return b_ih[gu] + b_hh[gu];
    if (k >= 312) return W_ih[gu * 8 + (k - 312)];
    return 0.f;
}
__device__ __forceinline__ float wa_val(int s, int kt, int lane, int e,
                                        const float* W_ta, const float* W_out) {
    if (s == 0) return 0.f;
    int u = lane & 15;
    int k = kt * 32 + ((lane >> 4) << 3) + e;
    if (k >= 300 || u > 12) return 0.f;
    if (u < 12) return W_ta[(size_t)u * 3600 + (s - 1) * 300 + k];
    return W_out[k];
}

__global__ __launch_bounds__(256) void prep_k(const float* __restrict__ bn_gamma,
                                              const float* __restrict__ bn_beta,
                                              const float* __restrict__ W_ih,
                                              const float* __restrict__ b_ih,
                                              const float* __restrict__ W_hh,
                                              const float* __restrict__ b_hh,
                                              const float* __restrict__ W_ta,
                                              const float* __restrict__ W_out,
                                              float* __restrict__ ws) {
    int idx = blockIdx.x * 256 + threadIdx.x;
    uint* wsu = (uint*)ws;
    if (idx < WG_U32) {
        // layout: [q200][nq4][half2][lane64][4u32]
        int word = idx & 3;
        int lane = (idx >> 2) & 63;
        int half = (idx >> 8) & 1;
        int nq   = (idx >> 9) & 3;
        int q    = idx >> 11;          // 0..199
        int kt   = q / 20, c = q % 20;
        int tile = nq * 20 + c;
        int e0 = word * 2;
        float v0 = wg_val(kt, tile, lane, e0,     W_hh, W_ih, b_ih, b_hh);
        float v1 = wg_val(kt, tile, lane, e0 + 1, W_hh, W_ih, b_ih, b_hh);
        uint h0 = f2b(v0), l0 = f2b(v0 - b2f(h0));
        uint h1 = f2b(v1), l1 = f2b(v1 - b2f(h1));
        uint b0 = half ? l0 : h0, b1 = half ? l1 : h1;
        wsu[OFF_WG + idx] = b0 | (b1 << 16);
        return;
    }
    int i2 = idx - WG_U32;
    if (i2 < WA_U32) {
        int word = i2 & 7;  int entry = i2 >> 3;
        int lane = entry & 63; int e2 = entry >> 6;
        int kt = e2 % 10;   int s = e2 / 10;
        int e0 = (word & 3) * 2; int isLo = word >> 2;
        float v0 = wa_val(s, kt, lane, e0,     W_ta, W_out);
        float v1 = wa_val(s, kt, lane, e0 + 1, W_ta, W_out);
        uint h0 = f2b(v0), l0 = f2b(v0 - b2f(h0));
        uint h1 = f2b(v1), l1 = f2b(v1 - b2f(h1));
        uint b0 = isLo ? l0 : h0, b1 = isLo ? l1 : h1;
        wsu[OFF_WA + i2] = b0 | (b1 << 16);
        return;
    }
    int i5 = i2 - WA_U32;
    if (i5 < 96) {
        float s1 = 0.f, s2 = 0.f;
        for (int b = 0; b < 512; ++b) {
            s1 += ws[OFF_PART + b * 192 + i5];
            s2 += ws[OFF_PART + b * 192 + 96 + i5];
        }
        float mu  = s1 * (1.f / 32768.f);
        float var = s2 * (1.f / 32768.f) - mu * mu;
        float rs  = rsqrtf(var + 1e-5f);
        float sc  = bn_gamma[i5] * rs;
        ws[OFF_SCALE + i5] = sc;
        ws[OFF_SHIFT + i5] = bn_beta[i5] - mu * sc;
    }
}

// ---------------- Kernel 3: fused everything ----------------
// 64 rows/block, 512 blocks, 8 waves = rh(2) x nq(4); each wave 2 row-tiles x
// 20 col-tiles (acc[40]). Barrier-free B pipeline: each wave privately stages
// its own 2KB chunk (1 col-tile hi+lo) into a per-wave ring-4 LDS buffer,
// 3 chunks ahead; self-sync via counted vmcnt(4) only. Waves drift freely
// within a step, interleaving LDS reads / DMA writes / MFMA across the CU.
__global__ __launch_bounds__(NT, 2) void mega_k(const float* __restrict__ x,
                                                const float* __restrict__ W_in,
                                                const float* __restrict__ W_sa,
                                                const float* __restrict__ b_sa,
                                                const float* __restrict__ b_ta,
                                                const float* __restrict__ ws,
                                                float* __restrict__ out) {
    extern __shared__ char smc[];
    ushort* h_hi  = (ushort*)(smc + L_HHI);
    ushort* h_lo  = (ushort*)(smc + L_HLO);
    float*  q_lds = (float*)(smc + L_Q);
    float*  ta_l  = (float*)(smc + L_TA);
    float*  scs   = (float*)(smc + L_SCS);
    float*  shs   = (float*)(smc + L_SHS);
    float*  wsa   = (float*)(smc + L_WSA);
    float*  bsa   = (float*)(smc + L_BSA);
    float*  Win   = (float*)smc;                  // phase-1 overlay [96][97]
    float*  xn    = (float*)(smc + L_B);          // phase-1 overlay [64][96]
    float*  yb    = (float*)(smc + L_B + 24576);  // phase-1 overlay [64][96]

    const int tid = threadIdx.x;
    const int gr0 = blockIdx.x * ROWS;

    // ---- phase 1: BN apply + input projection + spatial attention ----
    for (int i = tid; i < 96; i += NT) { scs[i] = ws[OFF_SCALE + i]; shs[i] = ws[OFF_SHIFT + i]; }
    for (int i = tid; i < 64; i += NT) wsa[i] = W_sa[i];
    for (int i = tid; i < 8;  i += NT) bsa[i] = b_sa[i];
    for (int i = tid; i < 96 * 96; i += NT) { int r = i / 96, c = i - r * 96; Win[r * 97 + c] = W_in[i]; }
    __syncthreads();
    for (int i = tid; i < ROWS * 96; i += NT) {
        int c = i % 96;
        xn[i] = x[(size_t)gr0 * 96 + i] * scs[c] + shs[c];
    }
    __syncthreads();
    for (int i = tid; i < ROWS * 96; i += NT) {
        int row = i / 96, col = i - row * 96;
        const float* xr = xn + row * 96;
        const float* wr = Win + col * 97;
        float acc = 0.f;
        #pragma unroll 8
        for (int jj = 0; jj < 96; ++jj) acc += xr[jj] * wr[jj];
        yb[i] = acc;
    }
    __syncthreads();
    for (int p = tid; p < ROWS * SEQN; p += NT) {
        int row = p / 12, s = p - row * 12;
        float* yv = yb + row * 96 + s * 8;
        float y[8], e[8];
        #pragma unroll
        for (int jj = 0; jj < 8; ++jj) y[jj] = yv[jj];
        float mx = -1e30f;
        #pragma unroll
        for (int jj = 0; jj < 8; ++jj) {
            float a = bsa[jj];
            #pragma unroll
            for (int ii = 0; ii < 8; ++ii) a += y[ii] * wsa[jj * 8 + ii];
            a = sigm_(a);
            e[jj] = a; mx = fmaxf(mx, a);
        }
        float den = 0.f;
        #pragma unroll
        for (int jj = 0; jj < 8; ++jj) { e[jj] = __expf(e[jj] - mx); den += e[jj]; }
        float inv = 1.f / den;
        #pragma unroll
        for (int jj = 0; jj < 8; ++jj) yv[jj] = y[jj] * e[jj] * inv;
    }
    __syncthreads();
    // pull this thread's 12 gated-input values into registers (frees y region),
    // and zero h arrays (retires the Win overlay)
    float xgv[12];
    {
        int row = tid >> 3, e = tid & 7;
        #pragma unroll
        for (int s = 0; s < SEQN; ++s) xgv[s] = yb[row * 96 + s * 8 + e];
    }
    for (int i = tid; i < ROWS * 320; i += NT) { h_hi[i] = 0; h_lo[i] = 0; }
    __syncthreads();
    // bias slot (unit 300 == 1.0) + xg slots for step 0 (units 312..319)
    for (int r = tid; r < ROWS; r += NT)
        *(ushort*)((char*)h_hi + haddr(r, 300)) = 0x3F80;
    {
        int row = tid >> 3, e = tid & 7;
        float v = xgv[0];
        uint hb = f2b(v), lb = f2b(v - b2f(hb));
        *(ushort*)((char*)h_hi + haddr(row, 312 + e)) = (ushort)hb;
        *(ushort*)((char*)h_lo + haddr(row, 312 + e)) = (ushort)lb;
    }

    // ---- phase 2: LSTM via split-bf16 MFMA, barrier-free private pipeline ----
    const int wv   = tid >> 6, lane = tid & 63;
    const int rh   = wv >> 2,  nq = wv & 3;
    const int rb   = rh * 32;
    const int a0   = rb + (lane & 15);              // A-row, row-tile 0
    const int a1   = a0 + 16;                       // A-row, row-tile 1
    const int d0   = rb + ((lane >> 4) << 2);       // D rows base, row-tile 0
    const int d1   = d0 + 16;                       // D rows base, row-tile 1
    const int lcol = lane & 15;
    const char* wgb     = (const char*)(ws + OFF_WG);
    const char* wa_lane = (const char*)(ws + OFF_WA) + (size_t)lane * 32;

    // private 2KB chunk = 1 col-tile (hi+lo) of this wave's nq slice
    #define STAGE(Q, BUF)                                                              \
        {   const char* s_ = wgb + (size_t)(Q) * 8192 + nq * 2048 + (size_t)lane * 16; \
            char* d_ = smc + L_B + wv * 8192 + (BUF) * 2048 + lane * 16;               \
            gload_lds16(s_, d_);                                                       \
            gload_lds16(s_ + 1024, d_ + 1024);                                         \
        }

    f32x4 acc[40];                                  // [rt*20 + c]
    f32x4 accA0 = {0.f, 0.f, 0.f, 0.f};
    f32x4 accA1 = {0.f, 0.f, 0.f, 0.f};
    float cst[40];
    #pragma unroll
    for (int t = 0; t < 40; ++t) cst[t] = 0.f;

    STAGE(0, 0);
    STAGE(1, 1);
    STAGE(2, 2);
    asm volatile("s_waitcnt lgkmcnt(0)" ::: "memory");   // h init visible; DMA stays in flight
    __builtin_amdgcn_s_barrier();
    __builtin_amdgcn_sched_barrier(0);

    #pragma unroll 1
    for (int s = 0; s < SEQN; ++s) {
        #pragma unroll
        for (int t = 0; t < 40; ++t) acc[t] = (f32x4){0.f, 0.f, 0.f, 0.f};

        #pragma unroll 1
        for (int kt = 0; kt < 10; ++kt) {
            const int koff = kt * 32 + ((lane >> 4) << 3);
            short8 ahi0 = *(const short8*)((const char*)h_hi + haddr(a0, koff));
            short8 alo0 = *(const short8*)((const char*)h_lo + haddr(a0, koff));
            short8 ahi1 = *(const short8*)((const char*)h_hi + haddr(a1, koff));
            short8 alo1 = *(const short8*)((const char*)h_lo + haddr(a1, koff));
            #pragma unroll
            for (int c = 0; c < 20; ++c) {
                // my chunk i = kt*20+c DMA landed (STAGE(i+1),(i+2) = 4 newer ops)
                asm volatile("s_waitcnt vmcnt(4)" ::: "memory");
                const char* bb = smc + L_B + wv * 8192 + (c & 3) * 2048 + (size_t)lane * 16;
                short8 bhi = *(const short8*)(bb);
                short8 blo = *(const short8*)(bb + 1024);
                // stage chunk i+3 into ring slot (c+3)&3 (its old contents: B(i-1),
                // already retired by MFMA(i-1)'s lgkm waits in program order)
                int qs = kt * 20 + c + 3;
                if (qs >= 200) qs -= 200;              // wraps across steps (table s-invariant)
                STAGE(qs, (c + 3) & 3);
                acc[c]      = __builtin_amdgcn_mfma_f32_16x16x32_bf16(ahi0, bhi, acc[c],      0, 0, 0);
                acc[20 + c] = __builtin_amdgcn_mfma_f32_16x16x32_bf16(ahi1, bhi, acc[20 + c], 0, 0, 0);
                acc[c]      = __builtin_amdgcn_mfma_f32_16x16x32_bf16(ahi0, blo, acc[c],      0, 0, 0);
                acc[20 + c] = __builtin_amdgcn_mfma_f32_16x16x32_bf16(ahi1, blo, acc[20 + c], 0, 0, 0);
                acc[c]      = __builtin_amdgcn_mfma_f32_16x16x32_bf16(alo0, bhi, acc[c],      0, 0, 0);
                acc[20 + c] = __builtin_amdgcn_mfma_f32_16x16x32_bf16(alo1, bhi, acc[20 + c], 0, 0, 0);
            }
        }
        // attention (waves with nq==3), h still h_s here
        if (nq == 3) {
            #pragma unroll 1
            for (int kt = 0; kt < 10; ++kt) {
                const int koff = kt * 32 + ((lane >> 4) << 3);
                short8 ahi0 = *(const short8*)((const char*)h_hi + haddr(a0, koff));
                short8 alo0 = *(const short8*)((const char*)h_lo + haddr(a0, koff));
                short8 ahi1 = *(const short8*)((const char*)h_hi + haddr(a1, koff));
                short8 alo1 = *(const short8*)((const char*)h_lo + haddr(a1, koff));
                const char* ap = wa_lane + (size_t)(s * 10 + kt) * 2048;
                short8 bhi = *(const short8*)(ap);
                short8 blo = *(const short8*)(ap + 16);
                accA0 = __builtin_amdgcn_mfma_f32_16x16x32_bf16(ahi0, bhi, accA0, 0, 0, 0);
                accA1 = __builtin_amdgcn_mfma_f32_16x16x32_bf16(ahi1, bhi, accA1, 0, 0, 0);
                accA0 = __builtin_amdgcn_mfma_f32_16x16x32_bf16(ahi0, blo, accA0, 0, 0, 0);
                accA1 = __builtin_amdgcn_mfma_f32_16x16x32_bf16(ahi1, blo, accA1, 0, 0, 0);
                accA0 = __builtin_amdgcn_mfma_f32_16x16x32_bf16(alo0, bhi, accA0, 0, 0, 0);
                accA1 = __builtin_amdgcn_mfma_f32_16x16x32_bf16(alo1, bhi, accA1, 0, 0, 0);
            }
        }
        // all h reads complete before overwrite (LDS-only drain; DMA stays in flight)
        asm volatile("s_waitcnt lgkmcnt(0)" ::: "memory");
        __builtin_amdgcn_s_barrier();
        __builtin_amdgcn_sched_barrier(0);

        // activation + h write (gate g at acc[rt*20+us*4+g], same lane/reg)
        #pragma unroll
        for (int rt = 0; rt < 2; ++rt) {
            const int db = rt ? d1 : d0;
            #pragma unroll
            for (int us = 0; us < 5; ++us) {
                int u = nq * 80 + us * 16 + lcol;
                bool live = (u < 300);
                #pragma unroll
                for (int r = 0; r < 4; ++r) {
                    float iv = sigm_(acc[rt * 20 + us * 4 + 0][r]);
                    float fv = sigm_(acc[rt * 20 + us * 4 + 1][r]);
                    float gv = tanh_(acc[rt * 20 + us * 4 + 2][r]);
                    float ov = sigm_(acc[rt * 20 + us * 4 + 3][r]);
                    float cn = fv * cst[rt * 20 + us * 4 + r] + iv * gv;
                    cst[rt * 20 + us * 4 + r] = cn;
                    float hv = ov * tanh_(cn);
                    if (live) {
                        int row = db + r;
                        uint hb = f2b(hv), lb = f2b(hv - b2f(hb));
                        *(ushort*)((char*)h_hi + haddr(row, u)) = (ushort)hb;
                        *(ushort*)((char*)h_lo + haddr(row, u)) = (ushort)lb;
                    }
                }
            }
        }
        // q extraction (col 12 of attention tile) + per-step reset
        if (nq == 3 && lcol == 12) {
            #pragma unroll
            for (int r = 0; r < 4; ++r) {
                if (s >= 1) {
                    q_lds[(d0 + r) * 12 + (s - 1)] = accA0[r];
                    q_lds[(d1 + r) * 12 + (s - 1)] = accA1[r];
                }
                accA0[r] = 0.f;
                accA1[r] = 0.f;
            }
        }
        // xg slots for next step (from registers)
        if (s < SEQN - 1) {
            int row = tid >> 3, e = tid & 7;
            float v = xgv[s + 1];
            uint hb = f2b(v), lb = f2b(v - b2f(hb));
            *(ushort*)((char*)h_hi + haddr(row, 312 + e)) = (ushort)hb;
            *(ushort*)((char*)h_lo + haddr(row, 312 + e)) = (ushort)lb;
        }
        asm volatile("s_waitcnt lgkmcnt(0)" ::: "memory");
        __builtin_amdgcn_s_barrier();
        __builtin_amdgcn_sched_barrier(0);
    }

    // ---- final attention pass for h_11 (table index s=12) ----
    if (nq == 3) {
        #pragma unroll 1
        for (int kt = 0; kt < 10; ++kt) {
            const int koff = kt * 32 + ((lane >> 4) << 3);
            short8 ahi0 = *(const short8*)((const char*)h_hi + haddr(a0, koff));
            short8 alo0 = *(const short8*)((const char*)h_lo + haddr(a0, koff));
            short8 ahi1 = *(const short8*)((const char*)h_hi + haddr(a1, koff));
            short8 alo1 = *(const short8*)((const char*)h_lo + haddr(a1, koff));
            const char* ap = wa_lane + (size_t)(12 * 10 + kt) * 2048;
            short8 bhi = *(const short8*)(ap);
            short8 blo = *(const short8*)(ap + 16);
            accA0 = __builtin_amdgcn_mfma_f32_16x16x32_bf16(ahi0, bhi, accA0, 0, 0, 0);
            accA1 = __builtin_amdgcn_mfma_f32_16x16x32_bf16(ahi1, bhi, accA1, 0, 0, 0);
            accA0 = __builtin_amdgcn_mfma_f32_16x16x32_bf16(ahi0, blo, accA0, 0, 0, 0);
            accA1 = __builtin_amdgcn_mfma_f32_16x16x32_bf16(ahi1, blo, accA1, 0, 0, 0);
            accA0 = __builtin_amdgcn_mfma_f32_16x16x32_bf16(alo0, bhi, accA0, 0, 0, 0);
            accA1 = __builtin_amdgcn_mfma_f32_16x16x32_bf16(alo1, bhi, accA1, 0, 0, 0);
        }
        if (lcol < 12) {
            #pragma unroll
            for (int r = 0; r < 4; ++r) {
                ta_l[(d0 + r) * 12 + lcol] = accA0[r];
                ta_l[(d1 + r) * 12 + lcol] = accA1[r];
            }
        } else if (lcol == 12) {
            #pragma unroll
            for (int r = 0; r < 4; ++r) {
                q_lds[(d0 + r) * 12 + 11] = accA0[r];
                q_lds[(d1 + r) * 12 + 11] = accA1[r];
            }
        }
    }
    __syncthreads();

    // ---- phase 3: softmax(relu(ta + b_ta)) and output ----
    if (tid < ROWS) {
        float l[12]; float mx = 0.f;
        #pragma unroll
        for (int s2 = 0; s2 < 12; ++s2) {
            float v = fmaxf(ta_l[tid * 12 + s2] + b_ta[s2], 0.f);
            l[s2] = v; mx = fmaxf(mx, v);
        }
        float den = 0.f, o = 0.f;
        #pragma unroll
        for (int s2 = 0; s2 < 12; ++s2) {
            float e = __expf(l[s2] - mx);
            den += e; o += e * q_lds[tid * 12 + s2];
        }
        out[gr0 + tid] = o / den;
    }
    #undef STAGE
}

extern "C" void kernel_launch(void* const* d_in, const int* in_sizes, int n_in,
                              void* d_out, int out_size, void* d_ws, size_t ws_size,
                              hipStream_t stream) {
    const float* x        = (const float*)d_in[0];
    const float* bn_gamma = (const float*)d_in[1];
    const float* bn_beta  = (const float*)d_in[2];
    const float* W_in     = (const float*)d_in[3];
    const float* W_sa     = (const float*)d_in[4];
    const float* b_sa     = (const float*)d_in[5];
    const float* W_ih     = (const float*)d_in[6];
    const float* b_ih     = (const float*)d_in[7];
    const float* W_hh     = (const float*)d_in[8];
    const float* b_hh     = (const float*)d_in[9];
    const float* W_ta     = (const float*)d_in[10];
    const float* b_ta     = (const float*)d_in[11];
    const float* W_out    = (const float*)d_in[12];
    float* ws  = (float*)d_ws;
    float* out = (float*)d_out;

    (void)in_sizes; (void)n_in; (void)out_size; (void)ws_size;

    (void)hipFuncSetAttribute((const void*)mega_k,
                              hipFuncAttributeMaxDynamicSharedMemorySize, SMEM_BYTES);

    bn_partial_k<<<512, 192, 0, stream>>>(x, ws);
    int prep_items = WG_U32 + WA_U32 + 96;
    prep_k<<<(prep_items + 255) / 256, 256, 0, stream>>>(bn_gamma, bn_beta, W_ih, b_ih,
                                                         W_hh, b_hh, W_ta, W_out, ws);
    mega_k<<<512, NT, SMEM_BYTES, stream>>>(x, W_in, W_sa, b_sa, b_ta, ws, out);
}

// Round 18
// 1283.105 us; speedup vs baseline: 1.0331x; 1.0331x over previous
//
#include <hip/hip_runtime.h>

typedef float  f32x4  __attribute__((ext_vector_type(4)));
typedef short  short8 __attribute__((ext_vector_type(8)));
typedef unsigned int uint;
typedef unsigned short ushort;

#define NT    512
#define SEQN  12
#define ROWS  64

// ws offsets (in 4-byte units)
#define OFF_PART   0          // [512][2][96] BN partials
#define OFF_SCALE  98304      // [96]
#define OFF_SHIFT  98400      // [96]
#define OFF_WG     98496      // 409600 u32: [q100][nq4][j2][half2][lane64][4u32]; q=kt*10+c
#define OFF_WA     508096     // 66560 u32:  [s13][kt10][lane64][8u32]

#define WG_U32     409600
#define WA_U32     66560

// LDS layout (bytes)
#define L_HHI   0          // [64][320] ushort, swizzled (40960)
#define L_HLO   40960      // [64][320] ushort (40960)
#define L_XG    81920      // [64][96] f32 (24576) — phase1 yb, then gated inputs
#define L_Q     106496     // [64][12] f32 (3072)
#define L_TA    109568     // [64][12] f32 (3072)
#define L_SCS   112640     // [96] f32
#define L_SHS   113024     // [96] f32
#define L_WSA   113408     // [8][8] f32
#define L_BSA   113664     // [8] f32
#define SMEM_BYTES 113696
// phase-1 overlays: Win [96][97] f32 (37248) inside h_hi (40960);
// xn [64][96] f32 (24576) inside h_lo (40960)

__device__ __forceinline__ float sigm_(float v) { return 1.f / (1.f + __expf(-v)); }
__device__ __forceinline__ float tanh_(float v) { float e = __expf(2.f * v); return 1.f - 2.f / (e + 1.f); }

__device__ __forceinline__ uint f2b(float v) {
    uint u = __float_as_uint(v);
    return (u + 0x7FFFu + ((u >> 16) & 1u)) >> 16;
}
__device__ __forceinline__ float b2f(uint b) { return __uint_as_float(b << 16); }
// swizzled byte offset into h arrays ([64][320] ushort)
__device__ __forceinline__ int haddr(int row, int u) {
    return ((row * 640 + u * 2) ^ ((row & 7) << 4));
}

// ---------------- Kernel 1: BN partial sums ----------------
__global__ __launch_bounds__(192) void bn_partial_k(const float* __restrict__ x,
                                                    float* __restrict__ ws) {
    __shared__ float sm[2][2][96];
    int t = threadIdx.x;
    int half = t / 96, f = t - half * 96;
    int r0 = blockIdx.x * 64 + half * 32;
    float s1 = 0.f, s2 = 0.f;
    for (int r = 0; r < 32; ++r) {
        float v = x[(size_t)(r0 + r) * 96 + f];
        s1 += v; s2 += v * v;
    }
    sm[half][0][f] = s1; sm[half][1][f] = s2;
    __syncthreads();
    if (t < 96) {
        ws[OFF_PART + blockIdx.x * 192 + t]      = sm[0][0][t] + sm[1][0][t];
        ws[OFF_PART + blockIdx.x * 192 + 96 + t] = sm[0][1][t] + sm[1][1][t];
    }
}

// ---------------- Kernel 2: build bf16-split fragment tables ----------------
// tile (0..79): nq = tile/20, rem = tile%20, us = rem/4, g = rem%4
__device__ __forceinline__ float wg_val(int kt, int tile, int lane, int e,
                                        const float* W_hh, const float* W_ih,
                                        const float* b_ih, const float* b_hh) {
    int nq = tile / 20, rem = tile % 20;
    int us = rem / 4, g = rem & 3;
    int u = nq * 80 + us * 16 + (lane & 15);
    int k = kt * 32 + ((lane >> 4) << 3) + e;
    if (u >= 300) return 0.f;
    int gu = g * 300 + u;
    if (k < 300)  return W_hh[(size_t)gu * 300 + k];
    if (k == 300) return b_ih[gu] + b_hh[gu];
    if (k >= 312) return W_ih[gu * 8 + (k - 312)];
    return 0.f;
}
__device__ __forceinline__ float wa_val(int s, int kt, int lane, int e,
                                        const float* W_ta, const float* W_out) {
    if (s == 0) return 0.f;
    int u = lane & 15;
    int k = kt * 32 + ((lane >> 4) << 3) + e;
    if (k >= 300 || u > 12) return 0.f;
    if (u < 12) return W_ta[(size_t)u * 3600 + (s - 1) * 300 + k];
    return W_out[k];
}

__global__ __launch_bounds__(256) void prep_k(const float* __restrict__ bn_gamma,
                                              const float* __restrict__ bn_beta,
                                              const float* __restrict__ W_ih,
                                              const float* __restrict__ b_ih,
                                              const float* __restrict__ W_hh,
                                              const float* __restrict__ b_hh,
                                              const float* __restrict__ W_ta,
                                              const float* __restrict__ W_out,
                                              float* __restrict__ ws) {
    int idx = blockIdx.x * 256 + threadIdx.x;
    uint* wsu = (uint*)ws;
    if (idx < WG_U32) {
        // layout: [q100][nq4][j2][half2][lane64][4u32]
        int word = idx & 3;
        int lane = (idx >> 2) & 63;
        int half = (idx >> 8) & 1;
        int j    = (idx >> 9) & 1;
        int nq   = (idx >> 10) & 3;
        int q    = idx >> 12;          // 0..99
        int kt   = q / 10, c = q % 10;
        int tile = nq * 20 + c * 2 + j;
        int e0 = word * 2;
        float v0 = wg_val(kt, tile, lane, e0,     W_hh, W_ih, b_ih, b_hh);
        float v1 = wg_val(kt, tile, lane, e0 + 1, W_hh, W_ih, b_ih, b_hh);
        uint h0 = f2b(v0), l0 = f2b(v0 - b2f(h0));
        uint h1 = f2b(v1), l1 = f2b(v1 - b2f(h1));
        uint b0 = half ? l0 : h0, b1 = half ? l1 : h1;
        wsu[OFF_WG + idx] = b0 | (b1 << 16);
        return;
    }
    int i2 = idx - WG_U32;
    if (i2 < WA_U32) {
        int word = i2 & 7;  int entry = i2 >> 3;
        int lane = entry & 63; int e2 = entry >> 6;
        int kt = e2 % 10;   int s = e2 / 10;
        int e0 = (word & 3) * 2; int isLo = word >> 2;
        float v0 = wa_val(s, kt, lane, e0,     W_ta, W_out);
        float v1 = wa_val(s, kt, lane, e0 + 1, W_ta, W_out);
        uint h0 = f2b(v0), l0 = f2b(v0 - b2f(h0));
        uint h1 = f2b(v1), l1 = f2b(v1 - b2f(h1));
        uint b0 = isLo ? l0 : h0, b1 = isLo ? l1 : h1;
        wsu[OFF_WA + i2] = b0 | (b1 << 16);
        return;
    }
    int i5 = i2 - WA_U32;
    if (i5 < 96) {
        float s1 = 0.f, s2 = 0.f;
        for (int b = 0; b < 512; ++b) {
            s1 += ws[OFF_PART + b * 192 + i5];
            s2 += ws[OFF_PART + b * 192 + 96 + i5];
        }
        float mu  = s1 * (1.f / 32768.f);
        float var = s2 * (1.f / 32768.f) - mu * mu;
        float rs  = rsqrtf(var + 1e-5f);
        float sc  = bn_gamma[i5] * rs;
        ws[OFF_SCALE + i5] = sc;
        ws[OFF_SHIFT + i5] = bn_beta[i5] - mu * sc;
    }
}

// ---------------- Kernel 3: fused everything ----------------
// 64 rows/block, 512 blocks, 8 waves = rh(2) x nq(4); each wave 2 row-tiles x
// 20 col-tiles (acc[40]); every loaded B pair feeds 6 MFMAs. B read directly
// from L2 into a static register ring pb[2][2][2], 1 chunk (2 pairs) ahead;
// no LDS staging, no chunk barriers — waves drift freely within a step.
__global__ __launch_bounds__(NT, 2) void mega_k(const float* __restrict__ x,
                                                const float* __restrict__ W_in,
                                                const float* __restrict__ W_sa,
                                                const float* __restrict__ b_sa,
                                                const float* __restrict__ b_ta,
                                                const float* __restrict__ ws,
                                                float* __restrict__ out) {
    extern __shared__ char smc[];
    ushort* h_hi  = (ushort*)(smc + L_HHI);
    ushort* h_lo  = (ushort*)(smc + L_HLO);
    float*  xg    = (float*)(smc + L_XG);
    float*  q_lds = (float*)(smc + L_Q);
    float*  ta_l  = (float*)(smc + L_TA);
    float*  scs   = (float*)(smc + L_SCS);
    float*  shs   = (float*)(smc + L_SHS);
    float*  wsa   = (float*)(smc + L_WSA);
    float*  bsa   = (float*)(smc + L_BSA);
    float*  Win   = (float*)smc;                  // phase-1 overlay [96][97] (in h_hi)
    float*  xn    = (float*)(smc + L_HLO);        // phase-1 overlay [64][96] (in h_lo)

    const int tid = threadIdx.x;
    const int gr0 = blockIdx.x * ROWS;

    // ---- phase 1: BN apply + input projection + spatial attention ----
    for (int i = tid; i < 96; i += NT) { scs[i] = ws[OFF_SCALE + i]; shs[i] = ws[OFF_SHIFT + i]; }
    for (int i = tid; i < 64; i += NT) wsa[i] = W_sa[i];
    for (int i = tid; i < 8;  i += NT) bsa[i] = b_sa[i];
    for (int i = tid; i < 96 * 96; i += NT) { int r = i / 96, c = i - r * 96; Win[r * 97 + c] = W_in[i]; }
    __syncthreads();
    for (int i = tid; i < ROWS * 96; i += NT) {
        int c = i % 96;
        xn[i] = x[(size_t)gr0 * 96 + i] * scs[c] + shs[c];
    }
    __syncthreads();
    for (int i = tid; i < ROWS * 96; i += NT) {
        int row = i / 96, col = i - row * 96;
        const float* xr = xn + row * 96;
        const float* wr = Win + col * 97;
        float acc = 0.f;
        #pragma unroll 8
        for (int jj = 0; jj < 96; ++jj) acc += xr[jj] * wr[jj];
        xg[i] = acc;
    }
    __syncthreads();
    for (int p = tid; p < ROWS * SEQN; p += NT) {
        int row = p / 12, s = p - row * 12;
        float* yv = xg + row * 96 + s * 8;
        float y[8], e[8];
        #pragma unroll
        for (int jj = 0; jj < 8; ++jj) y[jj] = yv[jj];
        float mx = -1e30f;
        #pragma unroll
        for (int jj = 0; jj < 8; ++jj) {
            float a = bsa[jj];
            #pragma unroll
            for (int ii = 0; ii < 8; ++ii) a += y[ii] * wsa[jj * 8 + ii];
            a = sigm_(a);
            e[jj] = a; mx = fmaxf(mx, a);
        }
        float den = 0.f;
        #pragma unroll
        for (int jj = 0; jj < 8; ++jj) { e[jj] = __expf(e[jj] - mx); den += e[jj]; }
        float inv = 1.f / den;
        #pragma unroll
        for (int jj = 0; jj < 8; ++jj) yv[jj] = y[jj] * e[jj] * inv;
    }
    __syncthreads();
    // zero h arrays (retires Win/xn overlays; xg lives in its own region)
    for (int i = tid; i < ROWS * 320; i += NT) { h_hi[i] = 0; h_lo[i] = 0; }
    __syncthreads();
    // bias slot (unit 300 == 1.0) + xg slots for step 0 (units 312..319)
    for (int r = tid; r < ROWS; r += NT)
        *(ushort*)((char*)h_hi + haddr(r, 300)) = 0x3F80;
    {
        int row = tid >> 3, e = tid & 7;
        float v = xg[row * 96 + e];
        uint hb = f2b(v), lb = f2b(v - b2f(hb));
        *(ushort*)((char*)h_hi + haddr(row, 312 + e)) = (ushort)hb;
        *(ushort*)((char*)h_lo + haddr(row, 312 + e)) = (ushort)lb;
    }
    __syncthreads();

    // ---- phase 2: LSTM via split-bf16 MFMA, register-ring B pipeline ----
    const int wv   = tid >> 6, lane = tid & 63;
    const int rh   = wv >> 2,  nq = wv & 3;
    const int rb   = rh * 32;
    const int a0   = rb + (lane & 15);              // A-row, row-tile 0
    const int a1   = a0 + 16;                       // A-row, row-tile 1
    const int d0   = rb + ((lane >> 4) << 2);       // D rows base, row-tile 0
    const int d1   = d0 + 16;                       // D rows base, row-tile 1
    const int lcol = lane & 15;
    // per-wave base: chunk q at + q*16384; pair j at + j*2048; half at + 1024
    const char* wg_lane = (const char*)(ws + OFF_WG) + nq * 4096 + (size_t)lane * 16;
    const char* wa_lane = (const char*)(ws + OFF_WA) + (size_t)lane * 32;

    f32x4 acc[40];                                  // [rt*20 + c*2 + j]
    f32x4 accA0 = {0.f, 0.f, 0.f, 0.f};
    f32x4 accA1 = {0.f, 0.f, 0.f, 0.f};
    float cst[40];
    #pragma unroll
    for (int t = 0; t < 40; ++t) cst[t] = 0.f;

    // register ring: pb[parity][j][half], all indices compile-time
    short8 pb[2][2][2];
    #pragma unroll
    for (int j = 0; j < 2; ++j) {
        pb[0][j][0] = *(const short8*)(wg_lane + j * 2048);
        pb[0][j][1] = *(const short8*)(wg_lane + j * 2048 + 1024);
    }

    #pragma unroll 1
    for (int s = 0; s < SEQN; ++s) {
        #pragma unroll
        for (int t = 0; t < 40; ++t) acc[t] = (f32x4){0.f, 0.f, 0.f, 0.f};

        #pragma unroll 1
        for (int kt = 0; kt < 10; ++kt) {
            const int koff = kt * 32 + ((lane >> 4) << 3);
            short8 ahi0 = *(const short8*)((const char*)h_hi + haddr(a0, koff));
            short8 alo0 = *(const short8*)((const char*)h_lo + haddr(a0, koff));
            short8 ahi1 = *(const short8*)((const char*)h_hi + haddr(a1, koff));
            short8 alo1 = *(const short8*)((const char*)h_lo + haddr(a1, koff));
            #pragma unroll
            for (int c = 0; c < 10; ++c) {
                const int q  = kt * 10 + c;
                const int qn = (q == 99) ? 0 : q + 1;   // wraps across steps (table s-invariant)
                // prefetch next chunk into opposite parity (static indices)
                const char* np = wg_lane + (size_t)qn * 16384;
                pb[(c + 1) & 1][0][0] = *(const short8*)(np);
                pb[(c + 1) & 1][0][1] = *(const short8*)(np + 1024);
                pb[(c + 1) & 1][1][0] = *(const short8*)(np + 2048);
                pb[(c + 1) & 1][1][1] = *(const short8*)(np + 3072);
                #pragma unroll
                for (int j = 0; j < 2; ++j) {
                    const int tt = c * 2 + j;
                    short8 bhi = pb[c & 1][j][0];
                    short8 blo = pb[c & 1][j][1];
                    acc[tt]      = __builtin_amdgcn_mfma_f32_16x16x32_bf16(ahi0, bhi, acc[tt],      0, 0, 0);
                    acc[20 + tt] = __builtin_amdgcn_mfma_f32_16x16x32_bf16(ahi1, bhi, acc[20 + tt], 0, 0, 0);
                    acc[tt]      = __builtin_amdgcn_mfma_f32_16x16x32_bf16(ahi0, blo, acc[tt],      0, 0, 0);
                    acc[20 + tt] = __builtin_amdgcn_mfma_f32_16x16x32_bf16(ahi1, blo, acc[20 + tt], 0, 0, 0);
                    acc[tt]      = __builtin_amdgcn_mfma_f32_16x16x32_bf16(alo0, bhi, acc[tt],      0, 0, 0);
                    acc[20 + tt] = __builtin_amdgcn_mfma_f32_16x16x32_bf16(alo1, bhi, acc[20 + tt], 0, 0, 0);
                }
            }
        }
        // attention (waves with nq==3), h still h_s here
        if (nq == 3) {
            #pragma unroll 1
            for (int kt = 0; kt < 10; ++kt) {
                const int koff = kt * 32 + ((lane >> 4) << 3);
                short8 ahi0 = *(const short8*)((const char*)h_hi + haddr(a0, koff));
                short8 alo0 = *(const short8*)((const char*)h_lo + haddr(a0, koff));
                short8 ahi1 = *(const short8*)((const char*)h_hi + haddr(a1, koff));
                short8 alo1 = *(const short8*)((const char*)h_lo + haddr(a1, koff));
                const char* ap = wa_lane + (size_t)(s * 10 + kt) * 2048;
                short8 bhi = *(const short8*)(ap);
                short8 blo = *(const short8*)(ap + 16);
                accA0 = __builtin_amdgcn_mfma_f32_16x16x32_bf16(ahi0, bhi, accA0, 0, 0, 0);
                accA1 = __builtin_amdgcn_mfma_f32_16x16x32_bf16(ahi1, bhi, accA1, 0, 0, 0);
                accA0 = __builtin_amdgcn_mfma_f32_16x16x32_bf16(ahi0, blo, accA0, 0, 0, 0);
                accA1 = __builtin_amdgcn_mfma_f32_16x16x32_bf16(ahi1, blo, accA1, 0, 0, 0);
                accA0 = __builtin_amdgcn_mfma_f32_16x16x32_bf16(alo0, bhi, accA0, 0, 0, 0);
                accA1 = __builtin_amdgcn_mfma_f32_16x16x32_bf16(alo1, bhi, accA1, 0, 0, 0);
            }
        }
        // all h reads complete before overwrite
        asm volatile("s_waitcnt lgkmcnt(0)" ::: "memory");
        __builtin_amdgcn_s_barrier();
        __builtin_amdgcn_sched_barrier(0);

        // activation + h write (gate g at acc[rt*20+us*4+g], same lane/reg)
        #pragma unroll
        for (int rt = 0; rt < 2; ++rt) {
            const int db = rt ? d1 : d0;
            #pragma unroll
            for (int us = 0; us < 5; ++us) {
                int u = nq * 80 + us * 16 + lcol;
                bool live = (u < 300);
                #pragma unroll
                for (int r = 0; r < 4; ++r) {
                    float iv = sigm_(acc[rt * 20 + us * 4 + 0][r]);
                    float fv = sigm_(acc[rt * 20 + us * 4 + 1][r]);
                    float gv = tanh_(acc[rt * 20 + us * 4 + 2][r]);
                    float ov = sigm_(acc[rt * 20 + us * 4 + 3][r]);
                    float cn = fv * cst[rt * 20 + us * 4 + r] + iv * gv;
                    cst[rt * 20 + us * 4 + r] = cn;
                    float hv = ov * tanh_(cn);
                    if (live) {
                        int row = db + r;
                        uint hb = f2b(hv), lb = f2b(hv - b2f(hb));
                        *(ushort*)((char*)h_hi + haddr(row, u)) = (ushort)hb;
                        *(ushort*)((char*)h_lo + haddr(row, u)) = (ushort)lb;
                    }
                }
            }
        }
        // q extraction (col 12 of attention tile) + per-step reset
        if (nq == 3 && lcol == 12) {
            #pragma unroll
            for (int r = 0; r < 4; ++r) {
                if (s >= 1) {
                    q_lds[(d0 + r) * 12 + (s - 1)] = accA0[r];
                    q_lds[(d1 + r) * 12 + (s - 1)] = accA1[r];
                }
                accA0[r] = 0.f;
                accA1[r] = 0.f;
            }
        }
        // xg slots for next step
        if (s < SEQN - 1) {
            int row = tid >> 3, e = tid & 7;
            float v = xg[row * 96 + (s + 1) * 8 + e];
            uint hb = f2b(v), lb = f2b(v - b2f(hb));
            *(ushort*)((char*)h_hi + haddr(row, 312 + e)) = (ushort)hb;
            *(ushort*)((char*)h_lo + haddr(row, 312 + e)) = (ushort)lb;
        }
        asm volatile("s_waitcnt lgkmcnt(0)" ::: "memory");
        __builtin_amdgcn_s_barrier();
        __builtin_amdgcn_sched_barrier(0);
    }

    // ---- final attention pass for h_11 (table index s=12) ----
    if (nq == 3) {
        #pragma unroll 1
        for (int kt = 0; kt < 10; ++kt) {
            const int koff = kt * 32 + ((lane >> 4) << 3);
            short8 ahi0 = *(const short8*)((const char*)h_hi + haddr(a0, koff));
            short8 alo0 = *(const short8*)((const char*)h_lo + haddr(a0, koff));
            short8 ahi1 = *(const short8*)((const char*)h_hi + haddr(a1, koff));
            short8 alo1 = *(const short8*)((const char*)h_lo + haddr(a1, koff));
            const char* ap = wa_lane + (size_t)(12 * 10 + kt) * 2048;
            short8 bhi = *(const short8*)(ap);
            short8 blo = *(const short8*)(ap + 16);
            accA0 = __builtin_amdgcn_mfma_f32_16x16x32_bf16(ahi0, bhi, accA0, 0, 0, 0);
            accA1 = __builtin_amdgcn_mfma_f32_16x16x32_bf16(ahi1, bhi, accA1, 0, 0, 0);
            accA0 = __builtin_amdgcn_mfma_f32_16x16x32_bf16(ahi0, blo, accA0, 0, 0, 0);
            accA1 = __builtin_amdgcn_mfma_f32_16x16x32_bf16(ahi1, blo, accA1, 0, 0, 0);
            accA0 = __builtin_amdgcn_mfma_f32_16x16x32_bf16(alo0, bhi, accA0, 0, 0, 0);
            accA1 = __builtin_amdgcn_mfma_f32_16x16x32_bf16(alo1, bhi, accA1, 0, 0, 0);
        }
        if (lcol < 12) {
            #pragma unroll
            for (int r = 0; r < 4; ++r) {
                ta_l[(d0 + r) * 12 + lcol] = accA0[r];
                ta_l[(d1 + r) * 12 + lcol] = accA1[r];
            }
        } else if (lcol == 12) {
            #pragma unroll
            for (int r = 0; r < 4; ++r) {
                q_lds[(d0 + r) * 12 + 11] = accA0[r];
                q_lds[(d1 + r) * 12 + 11] = accA1[r];
            }
        }
    }
    __syncthreads();

    // ---- phase 3: softmax(relu(ta + b_ta)) and output ----
    if (tid < ROWS) {
        float l[12]; float mx = 0.f;
        #pragma unroll
        for (int s2 = 0; s2 < 12; ++s2) {
            float v = fmaxf(ta_l[tid * 12 + s2] + b_ta[s2], 0.f);
            l[s2] = v; mx = fmaxf(mx, v);
        }
        float den = 0.f, o = 0.f;
        #pragma unroll
        for (int s2 = 0; s2 < 12; ++s2) {
            float e = __expf(l[s2] - mx);
            den += e; o += e * q_lds[tid * 12 + s2];
        }
        out[gr0 + tid] = o / den;
    }
}

extern "C" void kernel_launch(void* const* d_in, const int* in_sizes, int n_in,
                              void* d_out, int out_size, void* d_ws, size_t ws_size,
                              hipStream_t stream) {
    const float* x        = (const float*)d_in[0];
    const float* bn_gamma = (const float*)d_in[1];
    const float* bn_beta  = (const float*)d_in[2];
    const float* W_in     = (const float*)d_in[3];
    const float* W_sa     = (const float*)d_in[4];
    const float* b_sa     = (const float*)d_in[5];
    const float* W_ih     = (const float*)d_in[6];
    const float* b_ih     = (const float*)d_in[7];
    const float* W_hh     = (const float*)d_in[8];
    const float* b_hh     = (const float*)d_in[9];
    const float* W_ta     = (const float*)d_in[10];
    const float* b_ta     = (const float*)d_in[11];
    const float* W_out    = (const float*)d_in[12];
    float* ws  = (float*)d_ws;
    float* out = (float*)d_out;

    (void)in_sizes; (void)n_in; (void)out_size; (void)ws_size;

    (void)hipFuncSetAttribute((const void*)mega_k,
                              hipFuncAttributeMaxDynamicSharedMemorySize, SMEM_BYTES);

    bn_partial_k<<<512, 192, 0, stream>>>(x, ws);
    int prep_items = WG_U32 + WA_U32 + 96;
    prep_k<<<(prep_items + 255) / 256, 256, 0, stream>>>(bn_gamma, bn_beta, W_ih, b_ih,
                                                         W_hh, b_hh, W_ta, W_out, ws);
    mega_k<<<512, NT, SMEM_BYTES, stream>>>(x, W_in, W_sa, b_sa, b_ta, ws, out);
}

// Round 19
// 718.694 us; speedup vs baseline: 1.8444x; 1.7853x over previous
//
#include <hip/hip_runtime.h>

typedef float    f32x4 __attribute__((ext_vector_type(4)));
typedef _Float16 h8    __attribute__((ext_vector_type(8)));
typedef unsigned int uint;
typedef unsigned short ushort;

#define NT    512
#define SEQN  12
#define ROWS  64

// ws offsets (in 4-byte units)
#define OFF_PART   0          // [512][2][96] BN partials
#define OFF_SCALE  98304      // [96]
#define OFF_SHIFT  98400      // [96]
#define OFF_WG     98496      // 204800 u32: [q50][nq4][j4][lane64][4u32]; q=kt*5+c4 (fp16)
#define OFF_WA     303296     // 33280 u32:  [s13][kt10][lane64][4u32] (fp16)

#define WG_U32     204800
#define WA_U32     33280

// LDS layout (bytes)
#define L_HH    0          // [64][320] ushort fp16, swizzled (40960)
#define L_B     40960      // 2 x 16384 staged B ring (32768)
#define L_XG    73728      // [64][96] f32 (24576)
#define L_Q     98304      // [64][12] f32 (3072)
#define L_TA    101376     // [64][12] f32 (3072)
#define L_SCS   104448     // [96] f32
#define L_SHS   104832     // [96] f32
#define L_WSA   105216     // [8][8] f32
#define L_BSA   105472     // [8] f32
#define SMEM_BYTES 105504
// phase-1 overlays: Win [96][97] f32 (37248) at byte 0 (inside h region);
// xn [64][96] f32 (24576) at L_B

__device__ __forceinline__ float sigm_(float v) { return 1.f / (1.f + __expf(-v)); }
__device__ __forceinline__ float tanh_(float v) { float e = __expf(2.f * v); return 1.f - 2.f / (e + 1.f); }

__device__ __forceinline__ ushort f2h_bits(float v) {
    _Float16 h = (_Float16)v;        // RTN convert
    ushort b;
    __builtin_memcpy(&b, &h, 2);
    return b;
}
// swizzled byte offset into h array ([64][320] ushort)
__device__ __forceinline__ int haddr(int row, int u) {
    return ((row * 640 + u * 2) ^ ((row & 7) << 4));
}

__device__ __forceinline__ void gload_lds16(const void* src, void* dst) {
    __builtin_amdgcn_global_load_lds((const __attribute__((address_space(1))) void*)src,
                                     (__attribute__((address_space(3))) void*)dst, 16, 0, 0);
}

// ---------------- Kernel 1: BN partial sums ----------------
__global__ __launch_bounds__(192) void bn_partial_k(const float* __restrict__ x,
                                                    float* __restrict__ ws) {
    __shared__ float sm[2][2][96];
    int t = threadIdx.x;
    int half = t / 96, f = t - half * 96;
    int r0 = blockIdx.x * 64 + half * 32;
    float s1 = 0.f, s2 = 0.f;
    for (int r = 0; r < 32; ++r) {
        float v = x[(size_t)(r0 + r) * 96 + f];
        s1 += v; s2 += v * v;
    }
    sm[half][0][f] = s1; sm[half][1][f] = s2;
    __syncthreads();
    if (t < 96) {
        ws[OFF_PART + blockIdx.x * 192 + t]      = sm[0][0][t] + sm[1][0][t];
        ws[OFF_PART + blockIdx.x * 192 + 96 + t] = sm[0][1][t] + sm[1][1][t];
    }
}

// ---------------- Kernel 2: build fp16 fragment tables ----------------
// tile (0..79): nq = tile/20, rem = tile%20, us = rem/4, g = rem%4
__device__ __forceinline__ float wg_val(int kt, int tile, int lane, int e,
                                        const float* W_hh, const float* W_ih,
                                        const float* b_ih, const float* b_hh) {
    int nq = tile / 20, rem = tile % 20;
    int us = rem / 4, g = rem & 3;
    int u = nq * 80 + us * 16 + (lane & 15);
    int k = kt * 32 + ((lane >> 4) << 3) + e;
    if (u >= 300) return 0.f;
    int gu = g * 300 + u;
    if (k < 300)  return W_hh[(size_t)gu * 300 + k];
    if (k == 300) return b_ih[gu] + b_hh[gu];
    if (k >= 312) return W_ih[gu * 8 + (k - 312)];
    return 0.f;
}
__device__ __forceinline__ float wa_val(int s, int kt, int lane, int e,
                                        const float* W_ta, const float* W_out) {
    if (s == 0) return 0.f;
    int u = lane & 15;
    int k = kt * 32 + ((lane >> 4) << 3) + e;
    if (k >= 300 || u > 12) return 0.f;
    if (u < 12) return W_ta[(size_t)u * 3600 + (s - 1) * 300 + k];
    return W_out[k];
}

__global__ __launch_bounds__(256) void prep_k(const float* __restrict__ bn_gamma,
                                              const float* __restrict__ bn_beta,
                                              const float* __restrict__ W_ih,
                                              const float* __restrict__ b_ih,
                                              const float* __restrict__ W_hh,
                                              const float* __restrict__ b_hh,
                                              const float* __restrict__ W_ta,
                                              const float* __restrict__ W_out,
                                              float* __restrict__ ws) {
    int idx = blockIdx.x * 256 + threadIdx.x;
    uint* wsu = (uint*)ws;
    if (idx < WG_U32) {
        // layout: [q50][nq4][j4][lane64][4u32]
        int word = idx & 3;
        int lane = (idx >> 2) & 63;
        int j    = (idx >> 8) & 3;
        int nq   = (idx >> 10) & 3;
        int q    = idx >> 12;          // 0..49
        int kt   = q / 5, c4 = q % 5;
        int tile = nq * 20 + c4 * 4 + j;
        int e0 = word * 2;
        float v0 = wg_val(kt, tile, lane, e0,     W_hh, W_ih, b_ih, b_hh);
        float v1 = wg_val(kt, tile, lane, e0 + 1, W_hh, W_ih, b_ih, b_hh);
        uint b0 = f2h_bits(v0), b1 = f2h_bits(v1);
        wsu[OFF_WG + idx] = b0 | (b1 << 16);
        return;
    }
    int i2 = idx - WG_U32;
    if (i2 < WA_U32) {
        // layout: [s13][kt10][lane64][4u32]
        int word = i2 & 3;
        int lane = (i2 >> 2) & 63;
        int lin  = i2 >> 8;            // 0..129
        int kt   = lin % 10;
        int s    = lin / 10;
        int e0 = word * 2;
        float v0 = wa_val(s, kt, lane, e0,     W_ta, W_out);
        float v1 = wa_val(s, kt, lane, e0 + 1, W_ta, W_out);
        uint b0 = f2h_bits(v0), b1 = f2h_bits(v1);
        wsu[OFF_WA + i2] = b0 | (b1 << 16);
        return;
    }
    int i5 = i2 - WA_U32;
    if (i5 < 96) {
        float s1 = 0.f, s2 = 0.f;
        for (int b = 0; b < 512; ++b) {
            s1 += ws[OFF_PART + b * 192 + i5];
            s2 += ws[OFF_PART + b * 192 + 96 + i5];
        }
        float mu  = s1 * (1.f / 32768.f);
        float var = s2 * (1.f / 32768.f) - mu * mu;
        float rs  = rsqrtf(var + 1e-5f);
        float sc  = bn_gamma[i5] * rs;
        ws[OFF_SCALE + i5] = sc;
        ws[OFF_SHIFT + i5] = bn_beta[i5] - mu * sc;
    }
}

// ---------------- Kernel 3: fused everything (fp16 single-MFMA) ----------------
// 64 rows/block, 512 blocks, 8 waves = rh(2) x nq(4); each wave 2 row-tiles x
// 20 col-tiles (acc[40]); one fp16 MFMA per (row-tile, col-tile). B staged via
// global_load_lds in 16KB chunks, ring-2, counted vmcnt(2) + raw barriers.
__global__ __launch_bounds__(NT, 2) void mega_k(const float* __restrict__ x,
                                                const float* __restrict__ W_in,
                                                const float* __restrict__ W_sa,
                                                const float* __restrict__ b_sa,
                                                const float* __restrict__ b_ta,
                                                const float* __restrict__ ws,
                                                float* __restrict__ out) {
    extern __shared__ char smc[];
    ushort* h_h   = (ushort*)(smc + L_HH);
    float*  xg    = (float*)(smc + L_XG);
    float*  q_lds = (float*)(smc + L_Q);
    float*  ta_l  = (float*)(smc + L_TA);
    float*  scs   = (float*)(smc + L_SCS);
    float*  shs   = (float*)(smc + L_SHS);
    float*  wsa   = (float*)(smc + L_WSA);
    float*  bsa   = (float*)(smc + L_BSA);
    float*  Win   = (float*)smc;                  // phase-1 overlay [96][97]
    float*  xn    = (float*)(smc + L_B);          // phase-1 overlay [64][96]

    const int tid = threadIdx.x;
    const int gr0 = blockIdx.x * ROWS;

    // ---- phase 1: BN apply + input projection + spatial attention ----
    for (int i = tid; i < 96; i += NT) { scs[i] = ws[OFF_SCALE + i]; shs[i] = ws[OFF_SHIFT + i]; }
    for (int i = tid; i < 64; i += NT) wsa[i] = W_sa[i];
    for (int i = tid; i < 8;  i += NT) bsa[i] = b_sa[i];
    for (int i = tid; i < 96 * 96; i += NT) { int r = i / 96, c = i - r * 96; Win[r * 97 + c] = W_in[i]; }
    __syncthreads();
    for (int i = tid; i < ROWS * 96; i += NT) {
        int c = i % 96;
        xn[i] = x[(size_t)gr0 * 96 + i] * scs[c] + shs[c];
    }
    __syncthreads();
    for (int i = tid; i < ROWS * 96; i += NT) {
        int row = i / 96, col = i - row * 96;
        const float* xr = xn + row * 96;
        const float* wr = Win + col * 97;
        float acc = 0.f;
        #pragma unroll 8
        for (int jj = 0; jj < 96; ++jj) acc += xr[jj] * wr[jj];
        xg[i] = acc;
    }
    __syncthreads();
    for (int p = tid; p < ROWS * SEQN; p += NT) {
        int row = p / 12, s = p - row * 12;
        float* yv = xg + row * 96 + s * 8;
        float y[8], e[8];
        #pragma unroll
        for (int jj = 0; jj < 8; ++jj) y[jj] = yv[jj];
        float mx = -1e30f;
        #pragma unroll
        for (int jj = 0; jj < 8; ++jj) {
            float a = bsa[jj];
            #pragma unroll
            for (int ii = 0; ii < 8; ++ii) a += y[ii] * wsa[jj * 8 + ii];
            a = sigm_(a);
            e[jj] = a; mx = fmaxf(mx, a);
        }
        float den = 0.f;
        #pragma unroll
        for (int jj = 0; jj < 8; ++jj) { e[jj] = __expf(e[jj] - mx); den += e[jj]; }
        float inv = 1.f / den;
        #pragma unroll
        for (int jj = 0; jj < 8; ++jj) yv[jj] = y[jj] * e[jj] * inv;
    }
    __syncthreads();
    // zero h array (retires Win overlay; xn overlay sits in B region)
    for (int i = tid; i < ROWS * 320; i += NT) h_h[i] = 0;
    __syncthreads();
    // bias slot (unit 300 == 1.0 fp16) + xg slots for step 0 (units 312..319)
    for (int r = tid; r < ROWS; r += NT)
        *(ushort*)((char*)h_h + haddr(r, 300)) = 0x3C00;
    {
        int row = tid >> 3, e = tid & 7;
        *(ushort*)((char*)h_h + haddr(row, 312 + e)) = f2h_bits(xg[row * 96 + e]);
    }
    __syncthreads();

    // ---- phase 2: LSTM via fp16 MFMA, pipelined LDS staging ----
    const int wv   = tid >> 6, lane = tid & 63;
    const int rh   = wv >> 2,  nq = wv & 3;
    const int rb   = rh * 32;
    const int a0   = rb + (lane & 15);              // A-row, row-tile 0
    const int a1   = a0 + 16;                       // A-row, row-tile 1
    const int d0   = rb + ((lane >> 4) << 2);       // D rows base, row-tile 0
    const int d1   = d0 + 16;                       // D rows base, row-tile 1
    const int lcol = lane & 15;
    const char* wgb     = (const char*)(ws + OFF_WG);
    const char* wa_lane = (const char*)(ws + OFF_WA) + (size_t)lane * 16;

    // chunk = 16KB = one (kt,c4) slice; per wave: 2 staging loads
    #define STAGE(Q, BUF)                                                              \
        {   _Pragma("unroll")                                                          \
            for (int i_ = 0; i_ < 2; ++i_) {                                           \
                const char* s_ = wgb + (size_t)(Q) * 16384 + (wv * 2 + i_) * 1024      \
                                      + (size_t)lane * 16;                             \
                char* d_ = smc + L_B + (BUF) * 16384 + (wv * 2 + i_) * 1024            \
                                + lane * 16;                                           \
                gload_lds16(s_, d_);                                                   \
            }                                                                          \
        }

    f32x4 acc[40];                                  // [rt*20 + us*4 + g]
    f32x4 accA0 = {0.f, 0.f, 0.f, 0.f};
    f32x4 accA1 = {0.f, 0.f, 0.f, 0.f};
    float cst[40];
    #pragma unroll
    for (int t = 0; t < 40; ++t) cst[t] = 0.f;

    STAGE(0, 0);
    asm volatile("s_waitcnt lgkmcnt(0)" ::: "memory");   // h init visible; DMA stays in flight
    __builtin_amdgcn_s_barrier();
    __builtin_amdgcn_sched_barrier(0);

    #pragma unroll 1
    for (int s = 0; s < SEQN; ++s) {
        #pragma unroll
        for (int t = 0; t < 40; ++t) acc[t] = (f32x4){0.f, 0.f, 0.f, 0.f};

        #pragma unroll 1
        for (int kt = 0; kt < 10; ++kt) {
            const int koff = kt * 32 + ((lane >> 4) << 3);
            h8 a0v = *(const h8*)((const char*)h_h + haddr(a0, koff));
            h8 a1v = *(const h8*)((const char*)h_h + haddr(a1, koff));
            #pragma unroll
            for (int c4 = 0; c4 < 5; ++c4) {
                const int q  = kt * 5 + c4;
                const int qn = (q == 49) ? 0 : q + 1;     // wraps across steps (table s-invariant)
                STAGE(qn, qn & 1);
                asm volatile("s_waitcnt vmcnt(2)" ::: "memory");   // my chunk-q loads landed
                __builtin_amdgcn_s_barrier();                       // everyone's landed
                __builtin_amdgcn_sched_barrier(0);
                const char* bb = smc + L_B + (q & 1) * 16384 + nq * 4096 + (size_t)lane * 16;
                #pragma unroll
                for (int j = 0; j < 4; ++j) {
                    const int tt = c4 * 4 + j;
                    h8 bv = *(const h8*)(bb + j * 1024);
                    acc[tt]      = __builtin_amdgcn_mfma_f32_16x16x32_f16(a0v, bv, acc[tt],      0, 0, 0);
                    acc[20 + tt] = __builtin_amdgcn_mfma_f32_16x16x32_f16(a1v, bv, acc[20 + tt], 0, 0, 0);
                }
            }
        }
        // attention (waves with nq==3), h still h_s here
        if (nq == 3) {
            #pragma unroll 1
            for (int kt = 0; kt < 10; ++kt) {
                const int koff = kt * 32 + ((lane >> 4) << 3);
                h8 a0v = *(const h8*)((const char*)h_h + haddr(a0, koff));
                h8 a1v = *(const h8*)((const char*)h_h + haddr(a1, koff));
                h8 bv  = *(const h8*)(wa_lane + (size_t)(s * 10 + kt) * 1024);
                accA0 = __builtin_amdgcn_mfma_f32_16x16x32_f16(a0v, bv, accA0, 0, 0, 0);
                accA1 = __builtin_amdgcn_mfma_f32_16x16x32_f16(a1v, bv, accA1, 0, 0, 0);
            }
        }
        // all h reads complete before overwrite (LDS-only drain; DMA stays in flight)
        asm volatile("s_waitcnt lgkmcnt(0)" ::: "memory");
        __builtin_amdgcn_s_barrier();
        __builtin_amdgcn_sched_barrier(0);

        // activation + h write (gate g at acc[rt*20+us*4+g], same lane/reg)
        #pragma unroll
        for (int rt = 0; rt < 2; ++rt) {
            const int db = rt ? d1 : d0;
            #pragma unroll
            for (int us = 0; us < 5; ++us) {
                int u = nq * 80 + us * 16 + lcol;
                bool live = (u < 300);
                #pragma unroll
                for (int r = 0; r < 4; ++r) {
                    float iv = sigm_(acc[rt * 20 + us * 4 + 0][r]);
                    float fv = sigm_(acc[rt * 20 + us * 4 + 1][r]);
                    float gv = tanh_(acc[rt * 20 + us * 4 + 2][r]);
                    float ov = sigm_(acc[rt * 20 + us * 4 + 3][r]);
                    float cn = fv * cst[rt * 20 + us * 4 + r] + iv * gv;
                    cst[rt * 20 + us * 4 + r] = cn;
                    float hv = ov * tanh_(cn);
                    if (live) {
                        int row = db + r;
                        *(ushort*)((char*)h_h + haddr(row, u)) = f2h_bits(hv);
                    }
                }
            }
        }
        // q extraction (col 12 of attention tile) + per-step reset
        if (nq == 3 && lcol == 12) {
            #pragma unroll
            for (int r = 0; r < 4; ++r) {
                if (s >= 1) {
                    q_lds[(d0 + r) * 12 + (s - 1)] = accA0[r];
                    q_lds[(d1 + r) * 12 + (s - 1)] = accA1[r];
                }
                accA0[r] = 0.f;
                accA1[r] = 0.f;
            }
        }
        // xg slots for next step
        if (s < SEQN - 1) {
            int row = tid >> 3, e = tid & 7;
            *(ushort*)((char*)h_h + haddr(row, 312 + e)) = f2h_bits(xg[row * 96 + (s + 1) * 8 + e]);
        }
        asm volatile("s_waitcnt lgkmcnt(0)" ::: "memory");
        __builtin_amdgcn_s_barrier();
        __builtin_amdgcn_sched_barrier(0);
    }

    // ---- final attention pass for h_11 (table index s=12) ----
    if (nq == 3) {
        #pragma unroll 1
        for (int kt = 0; kt < 10; ++kt) {
            const int koff = kt * 32 + ((lane >> 4) << 3);
            h8 a0v = *(const h8*)((const char*)h_h + haddr(a0, koff));
            h8 a1v = *(const h8*)((const char*)h_h + haddr(a1, koff));
            h8 bv  = *(const h8*)(wa_lane + (size_t)(12 * 10 + kt) * 1024);
            accA0 = __builtin_amdgcn_mfma_f32_16x16x32_f16(a0v, bv, accA0, 0, 0, 0);
            accA1 = __builtin_amdgcn_mfma_f32_16x16x32_f16(a1v, bv, accA1, 0, 0, 0);
        }
        if (lcol < 12) {
            #pragma unroll
            for (int r = 0; r < 4; ++r) {
                ta_l[(d0 + r) * 12 + lcol] = accA0[r];
                ta_l[(d1 + r) * 12 + lcol] = accA1[r];
            }
        } else if (lcol == 12) {
            #pragma unroll
            for (int r = 0; r < 4; ++r) {
                q_lds[(d0 + r) * 12 + 11] = accA0[r];
                q_lds[(d1 + r) * 12 + 11] = accA1[r];
            }
        }
    }
    __syncthreads();

    // ---- phase 3: softmax(relu(ta + b_ta)) and output ----
    if (tid < ROWS) {
        float l[12]; float mx = 0.f;
        #pragma unroll
        for (int s2 = 0; s2 < 12; ++s2) {
            float v = fmaxf(ta_l[tid * 12 + s2] + b_ta[s2], 0.f);
            l[s2] = v; mx = fmaxf(mx, v);
        }
        float den = 0.f, o = 0.f;
        #pragma unroll
        for (int s2 = 0; s2 < 12; ++s2) {
            float e = __expf(l[s2] - mx);
            den += e; o += e * q_lds[tid * 12 + s2];
        }
        out[gr0 + tid] = o / den;
    }
    #undef STAGE
}

extern "C" void kernel_launch(void* const* d_in, const int* in_sizes, int n_in,
                              void* d_out, int out_size, void* d_ws, size_t ws_size,
                              hipStream_t stream) {
    const float* x        = (const float*)d_in[0];
    const float* bn_gamma = (const float*)d_in[1];
    const float* bn_beta  = (const float*)d_in[2];
    const float* W_in     = (const float*)d_in[3];
    const float* W_sa     = (const float*)d_in[4];
    const float* b_sa     = (const float*)d_in[5];
    const float* W_ih     = (const float*)d_in[6];
    const float* b_ih     = (const float*)d_in[7];
    const float* W_hh     = (const float*)d_in[8];
    const float* b_hh     = (const float*)d_in[9];
    const float* W_ta     = (const float*)d_in[10];
    const float* b_ta     = (const float*)d_in[11];
    const float* W_out    = (const float*)d_in[12];
    float* ws  = (float*)d_ws;
    float* out = (float*)d_out;

    (void)in_sizes; (void)n_in; (void)out_size; (void)ws_size;

    (void)hipFuncSetAttribute((const void*)mega_k,
                              hipFuncAttributeMaxDynamicSharedMemorySize, SMEM_BYTES);

    bn_partial_k<<<512, 192, 0, stream>>>(x, ws);
    int prep_items = WG_U32 + WA_U32 + 96;
    prep_k<<<(prep_items + 255) / 256, 256, 0, stream>>>(bn_gamma, bn_beta, W_ih, b_ih,
                                                         W_hh, b_hh, W_ta, W_out, ws);
    mega_k<<<512, NT, SMEM_BYTES, stream>>>(x, W_in, W_sa, b_sa, b_ta, ws, out);
}